// Round 1
// baseline (1553.799 us; speedup 1.0000x reference)
//
#include <hip/hip_runtime.h>
#include <cstdint>

#define T_ 4
#define B_ 16
#define C_ 384
#define N_ 1024
#define NG 16                  // groups of 64 columns
#define CN (C_*N_)             // 393216
#define BCN (B_*CN)            // 6291456
#define EPS 1e-5f

// workspace layout (bytes)
#define WQT_OFF   0u           // 384*384*4 = 589824
#define WPT_OFF   589824u
#define QINV_OFF  1179648u
#define QOFF_OFF  (QINV_OFF + 1536u)
#define PINV_OFF  (QINV_OFF + 3072u)
#define POFF_OFF  (QINV_OFF + 4608u)
#define C0_OFF    (QINV_OFF + 6144u)
#define XM_OFF    2097152u     // u64[4][16][16][384] = 3145728 B
#define MS_OFF    6291456u     // u64[4][16][16][384], ends 9437184

// ---------------- K0a: transpose wq, wp into ws ----------------
__global__ __launch_bounds__(256) void k0_transpose(const float* __restrict__ wq,
                                                    const float* __restrict__ wp,
                                                    char* __restrict__ ws) {
    int bid = blockIdx.x;
    const float* src = (bid < 576) ? wq : wp;
    float* dst = (float*)(ws + ((bid < 576) ? WQT_OFF : WPT_OFF));
    int i = (bid % 576) * 256 + threadIdx.x;     // 0..147455
    int c = i / 384, o = i % 384;
    dst[c * 384 + o] = src[o * 384 + c];
}

// ---------------- K0b: BN constants ----------------
__global__ void k0_consts(const float* __restrict__ qg, const float* __restrict__ qb,
                          const float* __restrict__ qm, const float* __restrict__ qv,
                          const float* __restrict__ pg, const float* __restrict__ pb,
                          const float* __restrict__ pm, const float* __restrict__ pv,
                          const float* __restrict__ bp, char* __restrict__ ws) {
    int i = threadIdx.x;                         // 384 threads
    float qi = qg[i] / sqrtf(qv[i] + EPS);
    ((float*)(ws + QINV_OFF))[i] = qi;
    ((float*)(ws + QOFF_OFF))[i] = qb[i] - qm[i] * qi;
    float pi = pg[i] / sqrtf(pv[i] + EPS);
    float po = pb[i] - pm[i] * pi;
    ((float*)(ws + PINV_OFF))[i] = pi;
    ((float*)(ws + POFF_OFF))[i] = po;
    ((float*)(ws + C0_OFF))[i] = bp[i] * pi + po;   // output value when GEMM2 input is all-zero
}

// ---------------- K1: shortcut LIF -> spike bitmasks ----------------
// wave w = (b, g, c); lane = n within 64-group; ballot packs spikes over n.
__global__ __launch_bounds__(256) void k1_lif(const float* __restrict__ x,
                                              unsigned long long* __restrict__ xm) {
    int wid  = (blockIdx.x * 256 + threadIdx.x) >> 6;   // 0..98303
    int lane = threadIdx.x & 63;
    int c = wid % 384;
    int g = (wid / 384) & 15;
    int b = wid / (384 * 16);
    const float* xp = x + (size_t)b * CN + (size_t)c * N_ + g * 64 + lane;
    float v = 0.f;
    #pragma unroll
    for (int t = 0; t < 4; ++t) {
        float xv = xp[(size_t)t * BCN];
        float h = v + (xv - v) * 0.5f;                  // v + (x - v)/tau, tau = 2
        bool s = (h >= 1.0f);
        unsigned long long m = __ballot(s);
        v = s ? 0.f : h;
        if (lane == 0) xm[(((size_t)t * 16 + b) * 16 + g) * 384 + c] = m;
    }
}

// ---------------- K2: sparse scatter GEMM1 + BN + q-LIF + attn mask ----------------
// block = (b, g, o-half); 192 threads, thread owns output channel o = oh*192+tid.
// LDS q[j][col]: column-private accumulation via ds_add_f32 (no contention).
__global__ __launch_bounds__(192) void k2_qpath(const float* __restrict__ wqT,
                                                const float* __restrict__ qinv_,
                                                const float* __restrict__ qoff_,
                                                const unsigned long long* __restrict__ xm,
                                                const unsigned char* __restrict__ ak,
                                                const unsigned char* __restrict__ av,
                                                unsigned long long* __restrict__ ms) {
    __shared__ __align__(16) float q[64 * 200];          // 51200 B
    __shared__ unsigned long long xmask[4 * 384];        // 12288 B
    int tid = threadIdx.x;
    int bid = blockIdx.x;
    int oh = bid & 1, g = (bid >> 1) & 15, b = bid >> 5;
    int o = oh * 192 + tid;

    for (int i = tid; i < 1536; i += 192) {
        int t = i / 384, c = i % 384;
        xmask[i] = xm[(((size_t)t * 16 + b) * 16 + g) * 384 + c];
    }
    float qi = qinv_[o], qo = qoff_[o];
    float vq[64];
    #pragma unroll
    for (int n = 0; n < 64; ++n) vq[n] = 0.f;
    __syncthreads();

    for (int t = 0; t < 4; ++t) {
        // zero accumulator tile
        for (int i = tid * 4; i < 12800; i += 192 * 4)
            *(float4*)(q + i) = make_float4(0.f, 0.f, 0.f, 0.f);
        __syncthreads();
        // scatter scan over input channels
        const unsigned long long* xmt = xmask + t * 384;
        for (int c = 0; c < 384; ++c) {
            unsigned long long m = xmt[c];
            if (m) {
                float w = wqT[c * 384 + o];
                do {
                    int j = __builtin_ctzll(m);
                    m &= m - 1;
                    atomicAdd(&q[j * 200 + tid], w);     // ds_add_f32, column-private
                } while (m);
            }
        }
        __syncthreads();
        // BN + LIF + attn mask epilogue (column-private reads)
        unsigned long long msk = 0ull;
        #pragma unroll
        for (int n = 0; n < 64; ++n) {
            float qbn = q[n * 200 + tid] * qi + qo;
            float h = vq[n] + (qbn - vq[n]) * 0.5f;
            bool s = (h >= 1.0f);
            vq[n] = s ? 0.f : h;
            if (s) {   // rare: only read attention masks where a spike exists
                size_t idx = (((size_t)t * 16 + b) * 384 + o) * 1024 + (size_t)g * 64 + n;
                s = (ak[idx] != 0) && (av[idx] != 0);
            }
            msk |= (unsigned long long)(s ? 1 : 0) << n;
        }
        ms[(((size_t)t * 16 + b) * 16 + g) * 384 + o] = msk;
        __syncthreads();
    }
}

// ---------------- K3: proj GEMM2 + bias + BN ----------------
// block = (t, b, g); fast path when the masked-spike tile is all-zero.
__global__ __launch_bounds__(384) void k3_proj(const float* __restrict__ wpT,
                                               const float* __restrict__ pinv_,
                                               const float* __restrict__ poff_,
                                               const float* __restrict__ bp,
                                               const float* __restrict__ c0,
                                               const unsigned long long* __restrict__ ms,
                                               float* __restrict__ out) {
    __shared__ __align__(16) float q[64 * 200];
    __shared__ unsigned long long mk[384];
    __shared__ int anyflag;
    int tid = threadIdx.x;
    int bid = blockIdx.x;
    int g = bid & 15, b = (bid >> 4) & 15, t = bid >> 8;
    if (tid == 0) anyflag = 0;
    unsigned long long m = ms[(((size_t)t * 16 + b) * 16 + g) * 384 + tid];
    mk[tid] = m;
    __syncthreads();
    if (m) anyflag = 1;        // benign race: all writers store 1
    __syncthreads();
    size_t obase = ((size_t)t * 16 + b) * 384;

    if (!anyflag) {
        // all-zero GEMM2 input: out = bp*inv + off, coalesced float4 stores
        #pragma unroll
        for (int k = 0; k < 16; ++k) {
            int i = tid + k * 384;            // 0..6143 float4 units in the (384o x 64n) tile
            int o = i >> 4, n4 = i & 15;
            float v = c0[o];
            float4* dst = (float4*)out + (obase + o) * 256 + g * 16 + n4;
            *dst = make_float4(v, v, v, v);
        }
        return;
    }
    // slow path (never taken on the bench input, correct in general)
    for (int half = 0; half < 2; ++half) {
        __syncthreads();
        for (int i = tid * 4; i < 12800; i += 384 * 4)
            *(float4*)(q + i) = make_float4(0.f, 0.f, 0.f, 0.f);
        __syncthreads();
        int active = (tid >= half * 192) && (tid < half * 192 + 192);
        int col = tid - half * 192;
        if (active) {
            for (int c = 0; c < 384; ++c) {
                unsigned long long mm = mk[c];
                if (mm) {
                    float w = wpT[c * 384 + tid];
                    do {
                        int j = __builtin_ctzll(mm);
                        mm &= mm - 1;
                        atomicAdd(&q[j * 200 + col], w);
                    } while (mm);
                }
            }
        }
        __syncthreads();
        if (active) {
            float pi = pinv_[tid], po = poff_[tid], bpo = bp[tid];
            for (int n = 0; n < 64; ++n) {
                float val = (q[n * 200 + col] + bpo) * pi + po;
                out[(obase + tid) * 1024 + (size_t)g * 64 + n] = val;
            }
        }
    }
}

extern "C" void kernel_launch(void* const* d_in, const int* in_sizes, int n_in,
                              void* d_out, int out_size, void* d_ws, size_t ws_size,
                              hipStream_t stream) {
    const float* x  = (const float*)d_in[0];
    const unsigned char* ak = (const unsigned char*)d_in[1];
    const unsigned char* av = (const unsigned char*)d_in[2];
    const float* wq = (const float*)d_in[3];
    const float* qg = (const float*)d_in[4];
    const float* qb = (const float*)d_in[5];
    const float* qm = (const float*)d_in[6];
    const float* qv = (const float*)d_in[7];
    const float* wp = (const float*)d_in[8];
    const float* bp = (const float*)d_in[9];
    const float* pg = (const float*)d_in[10];
    const float* pb = (const float*)d_in[11];
    const float* pm = (const float*)d_in[12];
    const float* pv = (const float*)d_in[13];
    char* ws = (char*)d_ws;
    float* out = (float*)d_out;

    hipLaunchKernelGGL(k0_transpose, dim3(1152), dim3(256), 0, stream, wq, wp, ws);
    hipLaunchKernelGGL(k0_consts, dim3(1), dim3(384), 0, stream,
                       qg, qb, qm, qv, pg, pb, pm, pv, bp, ws);
    hipLaunchKernelGGL(k1_lif, dim3(24576), dim3(256), 0, stream,
                       x, (unsigned long long*)(ws + XM_OFF));
    hipLaunchKernelGGL(k2_qpath, dim3(512), dim3(192), 0, stream,
                       (const float*)(ws + WQT_OFF), (const float*)(ws + QINV_OFF),
                       (const float*)(ws + QOFF_OFF),
                       (const unsigned long long*)(ws + XM_OFF), ak, av,
                       (unsigned long long*)(ws + MS_OFF));
    hipLaunchKernelGGL(k3_proj, dim3(1024), dim3(384), 0, stream,
                       (const float*)(ws + WPT_OFF), (const float*)(ws + PINV_OFF),
                       (const float*)(ws + POFF_OFF), bp, (const float*)(ws + C0_OFF),
                       (const unsigned long long*)(ws + MS_OFF), out);
}